// Round 1
// baseline (1219.227 us; speedup 1.0000x reference)
//
#include <hip/hip_runtime.h>
#include <math.h>

#define D_MODEL 512
#define ROWS_PER_BLOCK 256
#define THREADS 256

// digamma(x) for x >= 1, branch-free: shift by 6, then asymptotic series.
// psi(x) = psi(x+6) - sum_{k=0..5} 1/(x+k);  psi(z) ~ ln z - 1/(2z) - 1/(12 z^2) + 1/(120 z^4) - 1/(252 z^6)
__device__ __forceinline__ float digamma_ge1(float x) {
    float s = 0.0f;
#pragma unroll
    for (int k = 0; k < 6; ++k) {
        s += 1.0f / x;
        x += 1.0f;
    }
    float inv  = 1.0f / x;
    float inv2 = inv * inv;
    float series = inv2 * (1.0f/12.0f - inv2 * (1.0f/120.0f - inv2 * (1.0f/252.0f)));
    return logf(x) - 0.5f * inv - series - s;
}

__global__ __launch_bounds__(THREADS) void cah_kernel(
    const float* __restrict__ x,
    const int*   __restrict__ actors,
    const float* __restrict__ w,
    const float* __restrict__ bias,
    const int*   __restrict__ prev,
    float*       __restrict__ out,
    int n_actors)
{
    __shared__ float z0s[ROWS_PER_BLOCK];
    __shared__ float z1s[ROWS_PER_BLOCK];

    const int tid  = threadIdx.x;
    const int lane = tid & 63;
    const int wv   = tid >> 6;                       // wave id 0..3
    const int block_base = blockIdx.x * ROWS_PER_BLOCK;
    const int wave_base  = block_base + wv * 64;

    // --- Phase A: gather + dot, one row per wave-iteration (64 rows per wave) ---

    // Register-resident w fragments: lane covers cols [lane*4, lane*4+4) of each half.
    const float4 w0a = *reinterpret_cast<const float4*>(w + lane * 4);
    const float4 w0b = *reinterpret_cast<const float4*>(w + 256 + lane * 4);
    const float4 w1a = *reinterpret_cast<const float4*>(w + 512 + lane * 4);
    const float4 w1b = *reinterpret_cast<const float4*>(w + 768 + lane * 4);

    // Each lane preloads one actor index for this wave's 64 rows (broadcast later).
    int aidx = wave_base + lane;
    if (aidx >= n_actors) aidx = n_actors - 1;
    const int my_actor = actors[aidx];

    float4 xa, xb;
    {
        const int a0 = __shfl(my_actor, 0, 64);
        const float* rowp = x + (size_t)a0 * D_MODEL;
        xa = *reinterpret_cast<const float4*>(rowp + lane * 4);
        xb = *reinterpret_cast<const float4*>(rowp + 256 + lane * 4);
    }

#pragma unroll 4
    for (int j = 0; j < 64; ++j) {
        const float4 ca = xa, cb = xb;
        if (j < 63) {
            const int an = __shfl(my_actor, j + 1, 64);
            const float* rowp = x + (size_t)an * D_MODEL;
            xa = *reinterpret_cast<const float4*>(rowp + lane * 4);
            xb = *reinterpret_cast<const float4*>(rowp + 256 + lane * 4);
        }
        float s0 = fmaf(ca.x, w0a.x, fmaf(ca.y, w0a.y, fmaf(ca.z, w0a.z, ca.w * w0a.w)));
        s0 = fmaf(cb.x, w0b.x, fmaf(cb.y, w0b.y, fmaf(cb.z, w0b.z, fmaf(cb.w, w0b.w, s0))));
        float s1 = fmaf(ca.x, w1a.x, fmaf(ca.y, w1a.y, fmaf(ca.z, w1a.z, ca.w * w1a.w)));
        s1 = fmaf(cb.x, w1b.x, fmaf(cb.y, w1b.y, fmaf(cb.z, w1b.z, fmaf(cb.w, w1b.w, s1))));

#pragma unroll
        for (int off = 32; off; off >>= 1) {
            s0 += __shfl_xor(s0, off, 64);
            s1 += __shfl_xor(s1, off, 64);
        }
        if (lane == 0) {
            z0s[wv * 64 + j] = s0;
            z1s[wv * 64 + j] = s1;
        }
    }

    __syncthreads();

    // --- Phase B: per-row scalar math, one row per thread (fully lane-parallel) ---
    const int gid = block_base + tid;
    if (gid >= n_actors) return;

    const float z0 = z0s[tid] + bias[0];
    const float z1 = z1s[tid] + bias[1];
    const float a  = fmaf(z0, z0, 1.0f);
    const float bb = fmaf(z1, z1, 1.0f);

    const float pf = (float)prev[gid];
    const float INV_2P63 = 1.0f / 9223372036854775808.0f;   // 2^-63 (INT64_MAX rounds to 2^63 in f32)
    const float action = pf * INV_2P63;

    const float lbeta = lgammaf(a) + lgammaf(bb) - lgammaf(a + bb);
    const float logact = logf(action);
    const float log1m  = log1pf(-action);
    const float logprob = fmaf(a - 1.0f, logact, (bb - 1.0f) * log1m) - lbeta;

    const float entropy = lbeta
        - (a - 1.0f)  * digamma_ge1(a)
        - (bb - 1.0f) * digamma_ge1(bb)
        + (a + bb - 2.0f) * digamma_ge1(a + bb);

    out[gid] = pf;                              // action * INT64_MAX == (float)prev exactly
    out[(size_t)n_actors + gid] = logprob;
    out[(size_t)2 * n_actors + gid] = entropy;
    reinterpret_cast<float2*>(out + (size_t)3 * n_actors)[gid] = make_float2(a, bb);
}

extern "C" void kernel_launch(void* const* d_in, const int* in_sizes, int n_in,
                              void* d_out, int out_size, void* d_ws, size_t ws_size,
                              hipStream_t stream) {
    const float* x      = (const float*)d_in[0];
    const int*   actors = (const int*)  d_in[1];
    const float* w      = (const float*)d_in[2];
    const float* bias   = (const float*)d_in[3];
    const int*   prev   = (const int*)  d_in[4];
    float* out = (float*)d_out;

    const int n_actors = in_sizes[1];
    const int grid = (n_actors + ROWS_PER_BLOCK - 1) / ROWS_PER_BLOCK;

    hipLaunchKernelGGL(cah_kernel, dim3(grid), dim3(THREADS), 0, stream,
                       x, actors, w, bias, prev, out, n_actors);
}